// Round 6
// baseline (114.012 us; speedup 1.0000x reference)
//
#include <hip/hip_runtime.h>

#define NB 2
#define NC 16
#define NH 128
#define NW 256
#define NCW 32
#define HW (NH*NW)
#define PATCH_INV (1.0f/784.0f)
#define EPS_N 1e-9f

#define Y 4            // output rows per block
#define SW 64          // output cols per block (stripe)
#define LCOLS 104      // staged L cols [x0s-3, x0s+100]; 101 used, pad->104
#define RCOLS 72       // staged R cols [x0s-3, x0s+68];  70 used, pad->72
#define PCN 70         // prod cols [x0s-3, x0s+66]
#define RSTR 34        // ring/hprod row stride: 2-way banks (free), 8B-aligned pairs

// Block = (b, 4-row y-tile, 64-col stripe). 256 threads = 64 cols x 4 d-groups(8d).
// Per input row: stage L/R rows (all zero-padding HERE), per-row channel-dot ring
// + row-stat rings; per output row: fresh vertical 7-sum + horizontal 7-tap + norm.
__global__ __launch_bounds__(256) void ncc_kernel(
    const float* __restrict__ L, const float* __restrict__ R, float* __restrict__ out)
{
    __shared__ float ring[7][PCN][RSTR];          // prodrow ring  [slot][pc][d]
    __shared__ float hprod[PCN][RSTR];            // vertical sums [pc][d]
    __shared__ float Lrow[NC][LCOLS], Rrow[NC][RCOLS];
    __shared__ float srL[7][LCOLS], srL2[7][LCOLS];
    __shared__ float srR[7][RCOLS], srR2[7][RCOLS];
    __shared__ float SLv[LCOLS], SL2v[LCOLS], SRv[RCOLS], SR2v[RCOLS];
    __shared__ float sSL[LCOLS], sInvL[LCOLS], sSR[RCOLS], sInvR[RCOLS];

    // XCD swizzle: each XCD (bid&7) gets fixed b, fixed stripe-pair, 16 y-tiles
    const int bid  = blockIdx.x;
    const int xcd  = bid & 7, slot_id = bid >> 3;       // slot_id in [0,32)
    const int b    = xcd >> 2;
    const int xsp  = (xcd >> 1) & 1;
    const int yt   = (xcd & 1) * 16 + (slot_id >> 1);   // [0,32)
    const int xs   = xsp * 2 + (slot_id & 1);           // [0,4)
    const int y0   = yt * Y;
    const int x0s  = xs * SW;

    const int t  = threadIdx.x;
    const int dg = t >> 6;          // wave id, 0..3
    const int x  = t & 63;          // output col within stripe
    const int d0 = dg << 3;         // disparities d0..d0+7

    const size_t base = (size_t)b * NC * HW;

    for (int i = 0; i < Y + 6; ++i) {           // input rows y0-3 .. y0+Y+2
        const int yy = y0 - 3 + i;
        const int sl = i % 7;
        const bool rowok = (0 <= yy) && (yy < NH);
        const size_t rbase = base + (size_t)(rowok ? yy : 0) * NW;

        // ---- stage: ALL boundary zeroing happens here ----
        for (int idx = t; idx < NC * LCOLS; idx += 256) {
            int c = idx / LCOLS, lam = idx - c * LCOLS;
            int g = x0s - 3 + lam;
            float v = 0.f;
            if (rowok && 0 <= g && g < NW && lam < 101)
                v = L[rbase + (size_t)c * HW + g];
            Lrow[c][lam] = v;
        }
        for (int idx = t; idx < NC * RCOLS; idx += 256) {
            int c = idx / RCOLS, lam = idx - c * RCOLS;
            int g = x0s - 3 + lam;
            float v = 0.f;
            if (rowok && 0 <= g && g < NW && lam < 70)
                v = R[rbase + (size_t)c * HW + g];
            Rrow[c][lam] = v;
        }
        __syncthreads();   // S1: staged row visible

        // ---- row stats (channel sums per col) into stat rings ----
        if (t < LCOLS) {
            float s = 0.f, s2 = 0.f;
            #pragma unroll
            for (int c = 0; c < NC; ++c) { float v = Lrow[c][t]; s += v; s2 += v * v; }
            srL[sl][t] = s; srL2[sl][t] = s2;
        } else if (t < LCOLS + RCOLS) {
            int r = t - LCOLS;
            float s = 0.f, s2 = 0.f;
            #pragma unroll
            for (int c = 0; c < NC; ++c) { float v = Rrow[c][r]; s += v; s2 += v * v; }
            srR[sl][r] = s; srR2[sl][r] = s2;
        }

        // ---- main prod: pc = 3+x (global col x0s+x), 8 disparities ----
        {
            float vp[8];
            #pragma unroll
            for (int j = 0; j < 8; ++j) vp[j] = 0.f;
            #pragma unroll
            for (int c = 0; c < NC; ++c) {
                float rv = Rrow[c][x + 3];
                float lw[8];
                #pragma unroll
                for (int j = 0; j < 8; ++j) lw[j] = Lrow[c][x + d0 + 3 + j];
                #pragma unroll
                for (int j = 0; j < 8; ++j) vp[j] += lw[j] * rv;
            }
            #pragma unroll
            for (int j = 0; j < 8; ++j) ring[sl][3 + x][d0 + j] = vp[j];
        }
        // ---- halo prod: pc in {0,1,2,67,68,69}, all 32 d ----
        if (t < 192) {
            int hi = t >> 5;
            int pc = (hi < 3) ? hi : (64 + hi);
            int d  = t & 31;
            float s = 0.f;
            #pragma unroll
            for (int c = 0; c < NC; ++c) s += Lrow[c][pc + d] * Rrow[c][pc];
            ring[sl][pc][d] = s;
        }

        if (i >= 6) {
            const int yo = yy - 3;              // output row y0 + (i-6)
            __syncthreads();   // S2: ring + stat-ring writes visible

            // step A: vertical 7-sums (prod -> hprod, stats -> SLv/...)
            {
                float vs[8];
                #pragma unroll
                for (int j = 0; j < 8; ++j) vs[j] = 0.f;
                #pragma unroll
                for (int k = 0; k < 7; ++k)
                    #pragma unroll
                    for (int j = 0; j < 8; ++j) vs[j] += ring[k][3 + x][d0 + j];
                #pragma unroll
                for (int j = 0; j < 8; ++j) hprod[3 + x][d0 + j] = vs[j];
            }
            if (t < 192) {
                int hi = t >> 5;
                int pc = (hi < 3) ? hi : (64 + hi);
                int d  = t & 31;
                float s = 0.f;
                #pragma unroll
                for (int k = 0; k < 7; ++k) s += ring[k][pc][d];
                hprod[pc][d] = s;
            }
            if (t < LCOLS) {
                float s = 0.f, s2 = 0.f;
                #pragma unroll
                for (int k = 0; k < 7; ++k) { s += srL[k][t]; s2 += srL2[k][t]; }
                SLv[t] = s; SL2v[t] = s2;
            } else if (t < LCOLS + RCOLS) {
                int r = t - LCOLS;
                float s = 0.f, s2 = 0.f;
                #pragma unroll
                for (int k = 0; k < 7; ++k) { s += srR[k][r]; s2 += srR2[k][r]; }
                SRv[r] = s; SR2v[r] = s2;
            }
            __syncthreads();   // S3

            // step B: horizontal 7-tap on stats + rsqrt
            if (t >= 3 && t <= 97) {
                float s = 0.f, s2 = 0.f;
                #pragma unroll
                for (int k = -3; k <= 3; ++k) { s += SLv[t + k]; s2 += SL2v[t + k]; }
                sSL[t]   = s;
                sInvL[t] = rsqrtf(s2 - s * s * PATCH_INV + EPS_N);
            }
            if (t >= LCOLS + 3 && t <= LCOLS + 66) {
                int r = t - LCOLS;
                float s = 0.f, s2 = 0.f;
                #pragma unroll
                for (int k = -3; k <= 3; ++k) { s += SRv[r + k]; s2 += SR2v[r + k]; }
                sSR[r]   = s;
                sInvR[r] = rsqrtf(s2 - s * s * PATCH_INV + EPS_N);
            }
            __syncthreads();   // S4

            // step C: horizontal 7-tap on prod + normalize + store
            {
                const float srx = sSR[x + 3], irx = sInvR[x + 3];
                float res[8];
                #pragma unroll
                for (int j = 0; j < 8; ++j) {
                    float s = 0.f;
                    #pragma unroll
                    for (int k = 0; k < 7; ++k) s += hprod[x + k][d0 + j];
                    float slv = sSL[x + d0 + j + 3];
                    float ilv = sInvL[x + d0 + j + 3];
                    res[j] = (s - slv * srx * PATCH_INV) * ilv * irx;
                }
                float* op = out + (((size_t)(b * NH + yo) * NW) + x0s + x) * NCW + d0;
                *(float4*)op       = make_float4(res[0], res[1], res[2], res[3]);
                *(float4*)(op + 4) = make_float4(res[4], res[5], res[6], res[7]);
            }
        }
        __syncthreads();       // S5: reads done before next stage / ring overwrite
    }
}

extern "C" void kernel_launch(void* const* d_in, const int* in_sizes, int n_in,
                              void* d_out, int out_size, void* d_ws, size_t ws_size,
                              hipStream_t stream) {
    const float* Lp = (const float*)d_in[0];
    const float* Rp = (const float*)d_in[1];
    float* out = (float*)d_out;
    ncc_kernel<<<dim3(256), dim3(256), 0, stream>>>(Lp, Rp, out);
}

// Round 8
// 95.289 us; speedup vs baseline: 1.1965x; 1.1965x over previous
//
#include <hip/hip_runtime.h>

#define NB 2
#define NC 16
#define NH 128
#define NW 256
#define NCW 32
#define XE 262                    // ext prod cols: e = g+3, g in [-3, 258]
#define SLW 288                   // L-stat cols (287 used, padded)
#define HW (NH*NW)
#define PATCH_INV (1.0f/784.0f)
#define EPS_N 1e-9f

#define NPROD (NB*NH*XE*NCW)      // 2,146,304
#define NV    (NPROD/4)           //   536,576
#define NLS   (NB*NH*SLW)         //    73,728
#define NRS   (NB*NH*NW)          //    65,536

// workspace float offsets
#define PROD_OFF  0
#define VPROD_OFF (NPROD)
#define RSL_OFF   (2*NPROD)
#define RSL2_OFF  (RSL_OFF + NLS)
#define RSR_OFF   (RSL2_OFF + NLS)
#define RSR2_OFF  (RSR_OFF + NRS)
#define SSL_OFF   (RSR2_OFF + NRS)
#define SINVL_OFF (SSL_OFF + NLS)
#define SSR_OFF   (SINVL_OFF + NLS)
#define SINVR_OFF (SSR_OFF + NRS)

// ---- K1: per-row channel-dot products (lane = d) + per-row column stats ----
__global__ __launch_bounds__(256) void k1_prod_stats(
    const float* __restrict__ L, const float* __restrict__ R, float* __restrict__ ws)
{
    const int tid = blockIdx.x * 256 + threadIdx.x;
    if (tid < NPROD) {
        const int d  = tid & 31;
        const int r2 = tid >> 5;
        const int e  = r2 % XE;
        const int r3 = r2 / XE;            // b*NH + y
        const int b  = r3 >> 7, y = r3 & 127;
        const int g  = e - 3;
        const bool gok = (unsigned)g < NW;             // right col valid
        const int lcol = g + d;
        const bool lok = gok && (lcol < NW);           // left ext col nonzero
        const int ga = gok ? g : 0;
        const int la = lok ? lcol : 0;
        const size_t rowb = ((size_t)(b * NC) * NH + y) * NW;
        float vp = 0.f;
        #pragma unroll
        for (int c = 0; c < NC; ++c) {
            float lv = L[rowb + (size_t)c * HW + la];
            float rv = R[rowb + (size_t)c * HW + ga];
            lv = lok ? lv : 0.f;
            rv = gok ? rv : 0.f;
            vp += lv * rv;
        }
        ws[PROD_OFF + tid] = vp;           // layout [b][y][e][d] == tid
    } else if (tid < NPROD + NLS) {
        const int j  = tid - NPROD;
        const int xe = j % SLW;
        const int r3 = j / SLW;
        const int b  = r3 >> 7, y = r3 & 127;
        float s = 0.f, s2 = 0.f;
        if (xe < NW) {                     // ext cols >=256 are zero
            const size_t rowb = ((size_t)(b * NC) * NH + y) * NW + xe;
            #pragma unroll
            for (int c = 0; c < NC; ++c) {
                float v = L[rowb + (size_t)c * HW];
                s += v; s2 += v * v;
            }
        }
        ws[RSL_OFF + j] = s; ws[RSL2_OFF + j] = s2;
    } else {
        const int k  = tid - NPROD - NLS;
        const int x  = k & 255;
        const int r3 = k >> 8;
        const int b  = r3 >> 7, y = r3 & 127;
        const size_t rowb = ((size_t)(b * NC) * NH + y) * NW + x;
        float s = 0.f, s2 = 0.f;
        #pragma unroll
        for (int c = 0; c < NC; ++c) {
            float v = R[rowb + (size_t)c * HW];
            s += v; s2 += v * v;
        }
        ws[RSR_OFF + k] = s; ws[RSR2_OFF + k] = s2;
    }
}

// ---- K2: vertical 7-taps (prod -> vprod, float4) + stat finalize (7x7 + rsqrt) ----
__global__ __launch_bounds__(256) void k2_vertical(float* __restrict__ ws)
{
    const int tid = blockIdx.x * 256 + threadIdx.x;
    if (tid < NV) {
        const int q  = tid & 7;
        const int r2 = tid >> 3;
        const int e  = r2 % XE;
        const int r3 = r2 / XE;
        const int b  = r3 >> 7, y = r3 & 127;
        float4 acc = make_float4(0.f, 0.f, 0.f, 0.f);
        #pragma unroll
        for (int dy = -3; dy <= 3; ++dy) {
            const int yy = y + dy;
            if ((unsigned)yy < NH) {
                const float4 v = *(const float4*)&ws[PROD_OFF +
                    ((size_t)((b * NH + yy) * XE + e)) * NCW + 4 * q];
                acc.x += v.x; acc.y += v.y; acc.z += v.z; acc.w += v.w;
            }
        }
        *(float4*)&ws[VPROD_OFF + 4 * (size_t)tid] = acc;   // [b][y][e][d] == 4*tid
    } else if (tid < NV + NLS) {
        const int j  = tid - NV;
        const int xe = j % SLW;
        const int r3 = j / SLW;
        const int b  = r3 >> 7, y = r3 & 127;
        float S = 0.f, S2 = 0.f;
        #pragma unroll
        for (int dy = -3; dy <= 3; ++dy) {
            const int yy = y + dy;
            if ((unsigned)yy < NH) {
                const int rb = (b * NH + yy) * SLW;
                #pragma unroll
                for (int dx = -3; dx <= 3; ++dx) {
                    const int xx = xe + dx;
                    if ((unsigned)xx < SLW) {
                        S  += ws[RSL_OFF  + rb + xx];
                        S2 += ws[RSL2_OFF + rb + xx];
                    }
                }
            }
        }
        ws[SSL_OFF + j]   = S;
        ws[SINVL_OFF + j] = rsqrtf(S2 - S * S * PATCH_INV + EPS_N);
    } else {
        const int k  = tid - NV - NLS;
        const int x  = k & 255;
        const int r3 = k >> 8;
        const int b  = r3 >> 7, y = r3 & 127;
        float S = 0.f, S2 = 0.f;
        #pragma unroll
        for (int dy = -3; dy <= 3; ++dy) {
            const int yy = y + dy;
            if ((unsigned)yy < NH) {
                const int rb = (b * NH + yy) * NW;
                #pragma unroll
                for (int dx = -3; dx <= 3; ++dx) {
                    const int xx = x + dx;
                    if ((unsigned)xx < NW) {
                        S  += ws[RSR_OFF  + rb + xx];
                        S2 += ws[RSR2_OFF + rb + xx];
                    }
                }
            }
        }
        ws[SSR_OFF + k]   = S;
        ws[SINVR_OFF + k] = rsqrtf(S2 - S * S * PATCH_INV + EPS_N);
    }
}

// ---- K3: horizontal 7-tap on vprod + normalize + store (float4 per thread) ----
__global__ __launch_bounds__(256) void k3_horiz_norm(
    const float* __restrict__ ws, float* __restrict__ out)
{
    const int tid = blockIdx.x * 256 + threadIdx.x;   // < NB*NH*NW*8
    const int f  = tid & 7;                            // d-quad, d0 = 4f
    const int r2 = tid >> 3;
    const int x  = r2 & 255;
    const int r3 = r2 >> 8;
    const int b  = r3 >> 7, y = r3 & 127;

    const size_t vb = VPROD_OFF + ((size_t)((b * NH + y) * XE + x)) * NCW + 4 * f;
    float4 acc = make_float4(0.f, 0.f, 0.f, 0.f);
    #pragma unroll
    for (int dx = 0; dx < 7; ++dx) {                   // e = x..x+6 (g = x-3..x+3)
        const float4 v = *(const float4*)&ws[vb + (size_t)dx * NCW];
        acc.x += v.x; acc.y += v.y; acc.z += v.z; acc.w += v.w;
    }

    const int sb = (b * NH + y) * SLW + x + 4 * f;     // xe = x + d
    const float srx = ws[SSR_OFF  + (b * NH + y) * NW + x];
    const float irx = ws[SINVR_OFF + (b * NH + y) * NW + x];
    float4 res;
    res.x = (acc.x - ws[SSL_OFF + sb + 0] * srx * PATCH_INV) * ws[SINVL_OFF + sb + 0] * irx;
    res.y = (acc.y - ws[SSL_OFF + sb + 1] * srx * PATCH_INV) * ws[SINVL_OFF + sb + 1] * irx;
    res.z = (acc.z - ws[SSL_OFF + sb + 2] * srx * PATCH_INV) * ws[SINVL_OFF + sb + 2] * irx;
    res.w = (acc.w - ws[SSL_OFF + sb + 3] * srx * PATCH_INV) * ws[SINVL_OFF + sb + 3] * irx;

    *(float4*)&out[4 * (size_t)tid] = res;             // [b][y][x][d] == 4*tid
}

extern "C" void kernel_launch(void* const* d_in, const int* in_sizes, int n_in,
                              void* d_out, int out_size, void* d_ws, size_t ws_size,
                              hipStream_t stream) {
    const float* L = (const float*)d_in[0];
    const float* R = (const float*)d_in[1];
    float* out = (float*)d_out;
    float* ws  = (float*)d_ws;
    // exact grids: job counts are multiples of 256 (verified by static_assert)
    static_assert((NPROD + NLS + NRS) % 256 == 0, "K1 grid");
    static_assert((NV + NLS + NRS) % 256 == 0, "K2 grid");
    static_assert((NB*NH*NW*8) % 256 == 0, "K3 grid");
    k1_prod_stats<<<dim3((NPROD + NLS + NRS) / 256), dim3(256), 0, stream>>>(L, R, ws);
    k2_vertical  <<<dim3((NV + NLS + NRS) / 256),    dim3(256), 0, stream>>>(ws);
    k3_horiz_norm<<<dim3((NB*NH*NW*8) / 256),        dim3(256), 0, stream>>>(ws, out);
}